// Round 13
// baseline (161.715 us; speedup 1.0000x reference)
//
#include <hip/hip_runtime.h>

namespace {

typedef _Float16 half_t;
typedef _Float16 half2_t __attribute__((ext_vector_type(2)));
typedef _Float16 half4_t __attribute__((ext_vector_type(4)));
typedef _Float16 half8_t __attribute__((ext_vector_type(8)));

constexpr int Wd = 160, Hd = 192, Dd = 160;
constexpr int TX = 16, TY = 16, CZ = 80;
constexpr int HW = Hd * Wd;
constexpr int LIVE = CZ + 8;               // 88 slices per block
constexpr float INV_K = 1.0f / 729.0f;
constexpr float INV_TOT = 1.0f / 9830400.0f;   // 2*160*192*160
constexpr int R8 = 17;     // xs8 row stride in half8 units (16 cols + 1 pad)
constexpr int ROWS = 24;   // exactly the 16+8 y-halo rows needed

// ROUND 23: consumer REGISTER ring on the R22 producer/consumer base.
// R22 post-mortem: role split WON (88 -> 76 us profiled, bench 152, VGPR
// 72). Conflicts rose to 5.6M: the LDS z-ring's b128 ops at 2*tid (32B
// stride) hit 4 bank groups -> ~8-way conflict each slice; ring is also
// 23KB LDS + 4 of the consumer's 14 LDS ops. The R11/R16 register-ring
// failures were single-role threads holding 64-reg prefetch sets + ring;
// with roles SPLIT the union peaks ~110-135 regs, and at 480 blocks the
// GRID (1.875 blocks/CU) caps residency -- VGPR >128 is harmless here.
// So: ring -> consumer registers (9x half8 + 9x half2 = 45 VGPR, literal
// slot tokens via explicit 18-step expansion, the R16-proven pattern);
// (256,1) opens the budget so the allocator doesn't spill-force a cap.
// NOTE: any future CZ=40 (960-block) variant must re-tighten VGPR <= 128.
// INVARIANTS: WRITE_SIZE ~30 KB (MB-scale spill => revert), FETCH ~42 MB.

__global__ __launch_bounds__(256, 1)
void ncc_main(const float* __restrict__ inp, const float* __restrict__ tgt,
              float* __restrict__ out)
{
    __shared__ half8_t xs8[2][ROWS * R8];    // 2 x 6528 B: {II,IT,TT,I,T,-,-,-}
    __shared__ float   red[4];

    const int tid = threadIdx.x;

    // ---- XCD-aware remap (R17): 480 blocks = 8 x 60, bijective.
    const int lin = (int)blockIdx.x + 10 * (int)blockIdx.y + 120 * (int)blockIdx.z;
    const int swz = (lin & 7) * 60 + (lin >> 3);
    const int bx = swz % 10;
    const int by = (swz / 10) % 12;
    const int bz = swz / 120;

    const int n  = bz >> 1;
    const int zc = bz & 1;
    const int x0 = bx * TX, y0 = by * TY, z0 = zc * CZ;

    // ---- producer decode: tid 128..223 -> (row r 0..23) x (h,q col-group)
    const bool isProd = (tid >= 128) && (tid < 224);
    const int up = (tid >= 128) ? (tid - 128) : 0;
    const int r  = (up < 96) ? (up >> 2) : 0;
    const int hq = up & 3;
    const int h  = hq >> 1, qx = hq & 1;
    const int gy = y0 - 4 + r;
    const bool yok = (gy >= 0) && (gy < Hd);
    const int gyc = min(max(gy, 0), Hd - 1);
    const int gxs = x0 - 4 + 8 * h + 4 * qx;   // 12 input cols gxs..gxs+11

#define DECODE(c) \
    int voff##c; float m##c; \
    { const int gx = gxs + 4 * (c); \
      m##c = (yok && gx >= 0 && gx < Wd) ? 1.f : 0.f; \
      const int gxc = min(max(gx, 0), Wd - 4); \
      voff##c = gyc * Wd + gxc; }
    DECODE(0) DECODE(1) DECODE(2)
#undef DECODE

    const int nb = n * (Dd * HW);            // < 2^24, int math is exact
    const float* baseI = inp + nb;           // uniform -> SGPR pair
    const float* baseT = tgt + nb;

    // producer store bases: output cols col0..col0+3, half8 layout
    const int col0 = 8 * h + 4 * qx;
    half_t* const sb0 = (half_t*)xs8[0] + (r * R8 + col0) * 8;
    half_t* const sb1 = (half_t*)xs8[1] + (r * R8 + col0) * 8;

    // ---- consumer decode: tid<128 owns output pair (xi, 2yp),(xi, 2yp+1)
    const int xi = tid & 15;
    const int yp = (tid >> 4) & 7;
    const bool p2on = tid < 128;
    const half8_t* const rd8_0 = &xs8[0][(2 * yp) * R8 + xi];
    const half8_t* const rd8_1 = &xs8[1][(2 * yp) * R8 + xi];

    float4 S4a = make_float4(0.f, 0.f, 0.f, 0.f);
    float4 S4b = make_float4(0.f, 0.f, 0.f, 0.f);
    float STa = 0.f, STb = 0.f, acc = 0.f;

    // consumer z-ring in REGISTERS: slot index is a literal token everywhere
    half8_t rgA[9];
    half2_t rgT[9];
    #pragma unroll
    for (int q = 0; q < 9; ++q) { rgA[q] = (half8_t)0; rgT[q] = (half2_t)0; }

    // single producer prefetch set (depth-1; loads are L2-resident per R17)
    float4 SI0, SI1, SI2, ST0, ST1, ST2;
    SI0 = SI1 = SI2 = ST0 = ST1 = ST2 = make_float4(0.f, 0.f, 0.f, 0.f);

#define PRELOAD(zz) { \
    const float* pI = baseI + (zz) * HW; \
    const float* pT = baseT + (zz) * HW; \
    SI0 = *(const float4*)(pI + voff0); ST0 = *(const float4*)(pT + voff0); \
    SI1 = *(const float4*)(pI + voff1); ST1 = *(const float4*)(pT + voff1); \
    SI2 = *(const float4*)(pI + voff2); ST2 = *(const float4*)(pT + voff2); }

#define F4E(v, e) ((e) == 0 ? (v).x : ((e) == 1 ? (v).y : ((e) == 2 ? (v).z : (v).w)))

    // 9-tap sliding windows (4 outputs from 12 inputs), same fold as before
#define WIN4(PP, W) { \
    float ss = PP[0] + PP[1] + PP[2] + PP[3] + PP[4] + PP[5] + PP[6] + PP[7] + PP[8]; \
    W[0] = ss; ss += PP[9]  - PP[0]; W[1] = ss; \
               ss += PP[10] - PP[1]; W[2] = ss; \
               ss += PP[11] - PP[2]; W[3] = ss; }

    // compute + store one slice's x-windows (all 5 fields) to SBP
#define PRODUCE(SBP) { \
    float Im[12], Tr[12], p[12]; \
    float wII[4], wIT[4], wTT[4], wI[4], wT[4]; \
    _Pragma("unroll") \
    for (int e = 0; e < 4; ++e) { \
        Im[e]     = F4E(SI0, e) * m0;  Tr[e]     = fmaf(F4E(ST0, e), 0.5f, 0.5f); \
        Im[4 + e] = F4E(SI1, e) * m1;  Tr[4 + e] = fmaf(F4E(ST1, e), 0.5f, 0.5f); \
        Im[8 + e] = F4E(SI2, e) * m2;  Tr[8 + e] = fmaf(F4E(ST2, e), 0.5f, 0.5f); } \
    _Pragma("unroll") \
    for (int i = 0; i < 12; ++i) \
        p[i] = Im[i] * F4E((i < 4 ? SI0 : (i < 8 ? SI1 : SI2)), i & 3); \
    WIN4(p, wII) \
    _Pragma("unroll") \
    for (int i = 0; i < 12; ++i) p[i] = Im[i] * Tr[i]; \
    WIN4(p, wIT) \
    WIN4(Im, wI) \
    _Pragma("unroll") \
    for (int i = 0; i < 12; ++i) Im[i] = Tr[i] * (i < 4 ? m0 : (i < 8 ? m1 : m2)); \
    _Pragma("unroll") \
    for (int i = 0; i < 12; ++i) p[i] = Im[i] * Tr[i]; \
    WIN4(p, wTT) \
    WIN4(Im, wT) \
    _Pragma("unroll") \
    for (int cc = 0; cc < 4; ++cc) { \
        const half2_t v01 = {(half_t)wII[cc], (half_t)wIT[cc]}; \
        const half2_t v23 = {(half_t)wTT[cc], (half_t)wI[cc]}; \
        ((half2_t*)(SBP))[cc * 4]     = v01; \
        ((half2_t*)(SBP))[cc * 4 + 1] = v23; \
        (SBP)[cc * 8 + 4] = (half_t)wT[cc]; } }

    // ---- prologue: produce slice 0 into buf0; preload slice 1
    if (isProd) {
        if (z0 - 4 >= 0) { PRELOAD(z0 - 4) PRODUCE(sb0) }
        if (z0 - 3 >= 0) PRELOAD(z0 - 3)
    }
    __syncthreads();

    // one step: producer makes slice k+1, consumer eats slice k; 1 barrier.
    // UU = literal step 0..17, SL = literal UU%9 (register-ring slot).
#define STEP_BODY(UU, SL) { \
    const int k = tb + (UU); \
    if (isProd) { \
        const int zi1 = z0 - 3 + k;             /* z of slice k+1 */ \
        if ((k + 1) < LIVE && zi1 >= 0 && zi1 < Dd) { \
            if (((UU) & 1) == 0) PRODUCE(sb1) else PRODUCE(sb0) \
        } \
        const int zi2 = z0 - 2 + k;             /* z of slice k+2 */ \
        if ((k + 2) < LIVE && zi2 >= 0 && zi2 < Dd) PRELOAD(zi2) \
    } \
    { /* consumer: slice k from buf[k&1] */ \
        const int zi = z0 - 4 + k; \
        const bool zok = (zi >= 0) && (zi < Dd); \
        half2_t a01_0 = (half2_t)0, a23_0 = (half2_t)0; \
        half2_t a01_1 = (half2_t)0, a23_1 = (half2_t)0; \
        half_t aT0 = (half_t)0.f, aT1 = (half_t)0.f; \
        if (zok && p2on) { \
            const half8_t* const rd8 = (((UU) & 1) != 0) ? rd8_1 : rd8_0; \
            const half8_t w0 = rd8[0]; \
            const half8_t w9 = rd8[9 * R8]; \
            half2_t m01 = (half2_t)0, m23 = (half2_t)0, m4 = (half2_t)0; \
            _Pragma("unroll") \
            for (int kk = 1; kk < 9; ++kk) { \
                const half8_t w = rd8[kk * R8]; \
                const half2_t* wp = (const half2_t*)&w; \
                m01 += wp[0]; m23 += wp[1]; m4 += wp[2]; \
            } \
            const half2_t* w0p = (const half2_t*)&w0; \
            const half2_t* w9p = (const half2_t*)&w9; \
            a01_0 = m01 + w0p[0]; a23_0 = m23 + w0p[1]; aT0 = m4.x + w0p[2].x; \
            a01_1 = m01 + w9p[0]; a23_1 = m23 + w9p[1]; aT1 = m4.x + w9p[2].x; \
        } \
        if (p2on) {  /* register z-ring (static literal slot) */ \
            const half8_t oA = rgA[SL]; \
            const half2_t oT = rgT[SL]; \
            S4a.x += (float)a01_0.x - (float)oA[0]; \
            S4a.y += (float)a01_0.y - (float)oA[1]; \
            S4a.z += (float)a23_0.x - (float)oA[2]; \
            S4a.w += (float)a23_0.y - (float)oA[3]; \
            STa   += (float)aT0 - (float)oT.x; \
            S4b.x += (float)a01_1.x - (float)oA[4]; \
            S4b.y += (float)a01_1.y - (float)oA[5]; \
            S4b.z += (float)a23_1.x - (float)oA[6]; \
            S4b.w += (float)a23_1.y - (float)oA[7]; \
            STb   += (float)aT1 - (float)oT.y; \
            const half8_t nA = {a01_0.x, a01_0.y, a23_0.x, a23_0.y, \
                                a01_1.x, a01_1.y, a23_1.x, a23_1.y}; \
            rgA[SL] = nA; \
            const half2_t nT = {aT0, aT1}; \
            rgT[SL] = nT; \
        } \
        if (k >= 8 && p2on) {                   /* output z = z0+k-8 */ \
            { const float sii = S4a.x, sit = S4a.y, stt = S4a.z, si = S4a.w, stv = STa; \
              const float cross = sit - si * stv * INV_K; \
              const float tvar  = stt - stv * stv * INV_K; \
              const float ivar  = sii - si  * si  * INV_K; \
              acc += cross * cross * __builtin_amdgcn_rcpf(tvar * ivar + 1e-5f); } \
            { const float sii = S4b.x, sit = S4b.y, stt = S4b.z, si = S4b.w, stv = STb; \
              const float cross = sit - si * stv * INV_K; \
              const float tvar  = stt - stv * stv * INV_K; \
              const float ivar  = sii - si  * si  * INV_K; \
              acc += cross * cross * __builtin_amdgcn_rcpf(tvar * ivar + 1e-5f); } \
        } \
    } \
    __syncthreads(); }

#define STEP(UU, SL) if (tb + (UU) < LIVE) STEP_BODY(UU, SL)

    for (int tb = 0; tb < 90; tb += 18) {          // 88 live; 18-step x 5
        STEP(0, 0)  STEP(1, 1)  STEP(2, 2)  STEP(3, 3)  STEP(4, 4)
        STEP(5, 5)  STEP(6, 6)  STEP(7, 7)  STEP(8, 8)  STEP(9, 0)
        STEP(10, 1) STEP(11, 2) STEP(12, 3) STEP(13, 4) STEP(14, 5)
        STEP(15, 6) STEP(16, 7) STEP(17, 8)
    }
#undef STEP
#undef STEP_BODY
#undef PRODUCE
#undef WIN4
#undef F4E
#undef PRELOAD

    // ---- block reduction + fused finalize (one atomic per block)
    #pragma unroll
    for (int off = 32; off > 0; off >>= 1) acc += __shfl_down(acc, off, 64);
    if ((tid & 63) == 0) red[tid >> 6] = acc;
    __syncthreads();
    if (tid == 0) {
        const float tot = red[0] + red[1] + red[2] + red[3];
        atomicAdd(out, -tot * INV_TOT);
    }
}

} // namespace

extern "C" void kernel_launch(void* const* d_in, const int* in_sizes, int n_in,
                              void* d_out, int out_size, void* d_ws, size_t ws_size,
                              hipStream_t stream)
{
    const float* inp = (const float*)d_in[0];
    const float* tgt = (const float*)d_in[1];
    float* out = (float*)d_out;

    hipMemsetAsync(d_out, 0, sizeof(float), stream);   // d_out re-poisoned each call
    dim3 grid(Wd / TX, Hd / TY, 2 * (Dd / CZ));        // (10,12,4) = 480 blocks
    ncc_main<<<grid, 256, 0, stream>>>(inp, tgt, out);
}

// Round 14
// 156.053 us; speedup vs baseline: 1.0363x; 1.0363x over previous
//
#include <hip/hip_runtime.h>

namespace {

typedef _Float16 half_t;
typedef _Float16 half2_t __attribute__((ext_vector_type(2)));
typedef _Float16 half4_t __attribute__((ext_vector_type(4)));
typedef _Float16 half8_t __attribute__((ext_vector_type(8)));

constexpr int Wd = 160, Hd = 192, Dd = 160;
constexpr int TX = 16, TY = 16, CZ = 80;
constexpr int HW = Hd * Wd;
constexpr int LIVE = CZ + 8;               // 88 slices per block
constexpr int NSTEP = LIVE / 2;            // 44 paired steps
constexpr float INV_K = 1.0f / 729.0f;
constexpr float INV_TOT = 1.0f / 9830400.0f;   // 2*160*192*160
constexpr int R8 = 17;     // xs8 row stride in half8 units (16 cols + 1 pad)
constexpr int ROWS = 24;   // exactly the 16+8 y-halo rows needed

// ROUND 24: paired steps (2 slices per barrier) on the R22 split base.
// R23 post-mortem: register ring REFUTED twice over -- conflicts were
// bit-identical 5.6M without the LDS ring (they live in xs8 traffic, not
// the ring), and +45 consumer VGPRs serialized ds_read issue (76->86 us).
// Ring stays in LDS. R22 residual: VALU 38% / LDS ~31% / HBM 7%, grid-
// capped occupancy -- the unattacked term is 88 barriers/block of skew+
// drain. R13's pairing failure was the 128-VGPR cliff in the monolithic
// structure; at 480 blocks only 2 blocks/CU are needed (<=256 VGPR OK).
// This round: producer makes slices k+2,k+3 into 2 of 4 xs8 buffers (two
// preload sets A/B) while consumer eats k,k+1 from the other 2; ONE
// barrier per 2 slices (44+1 total). The two PRODUCEs are independent
// (different sets+buffers) -> ILP inside the longer step. Literal slot/
// buffer tokens via 18-step expansion (period lcm(9,2)=18; 18|54 trips).
// INVARIANTS: WRITE_SIZE ~30 KB, FETCH ~42 MB. VGPR may exceed 128 --
// harmless at THIS grid only (re-tighten if CZ/grid ever changes).

__global__ __launch_bounds__(256)
void ncc_main(const float* __restrict__ inp, const float* __restrict__ tgt,
              float* __restrict__ out)
{
    __shared__ half8_t xs8[4][ROWS * R8];    // 4 x 6528 B: {II,IT,TT,I,T,-,-,-}
    __shared__ half4_t ringAB[9 * 256];      // 18432 B: z-ring {II,IT,TT,I}
    __shared__ half_t  ringT[9 * 256];       //  4608 B: z-ring {T}
    __shared__ float   red[4];

    const int tid = threadIdx.x;

    // ---- XCD-aware remap (R17): 480 blocks = 8 x 60, bijective.
    const int lin = (int)blockIdx.x + 10 * (int)blockIdx.y + 120 * (int)blockIdx.z;
    const int swz = (lin & 7) * 60 + (lin >> 3);
    const int bx = swz % 10;
    const int by = (swz / 10) % 12;
    const int bz = swz / 120;

    const int n  = bz >> 1;
    const int zc = bz & 1;
    const int x0 = bx * TX, y0 = by * TY, z0 = zc * CZ;

    // zero the ring (all 256 entries per slot; prologue barrier orders it)
    #pragma unroll
    for (int q = 0; q < 9; ++q) {
        ringAB[q * 256 + tid] = (half4_t)0;
        ringT[q * 256 + tid] = (half_t)0.f;
    }

    // ---- producer decode: tid 128..223 -> (row r 0..23) x (h,q col-group)
    const bool isProd = (tid >= 128) && (tid < 224);
    const int up = (tid >= 128) ? (tid - 128) : 0;
    const int r  = (up < 96) ? (up >> 2) : 0;
    const int hq = up & 3;
    const int h  = hq >> 1, qx = hq & 1;
    const int gy = y0 - 4 + r;
    const bool yok = (gy >= 0) && (gy < Hd);
    const int gyc = min(max(gy, 0), Hd - 1);
    const int gxs = x0 - 4 + 8 * h + 4 * qx;   // 12 input cols gxs..gxs+11

#define DECODE(c) \
    int voff##c; float m##c; \
    { const int gx = gxs + 4 * (c); \
      m##c = (yok && gx >= 0 && gx < Wd) ? 1.f : 0.f; \
      const int gxc = min(max(gx, 0), Wd - 4); \
      voff##c = gyc * Wd + gxc; }
    DECODE(0) DECODE(1) DECODE(2)
#undef DECODE

    const int nb = n * (Dd * HW);            // < 2^24, int math is exact
    const float* baseI = inp + nb;           // uniform -> SGPR pair
    const float* baseT = tgt + nb;

    // producer store bases: output cols col0..col0+3, half8 layout, 4 bufs
    const int col0 = 8 * h + 4 * qx;
    half_t* const sb0 = (half_t*)xs8[0] + (r * R8 + col0) * 8;
    half_t* const sb1 = (half_t*)xs8[1] + (r * R8 + col0) * 8;
    half_t* const sb2 = (half_t*)xs8[2] + (r * R8 + col0) * 8;
    half_t* const sb3 = (half_t*)xs8[3] + (r * R8 + col0) * 8;

    // ---- consumer decode: tid<128 owns output pair (xi, 2yp),(xi, 2yp+1)
    const int xi = tid & 15;
    const int yp = (tid >> 4) & 7;
    const bool p2on = tid < 128;
    const half8_t* const rd8_0 = &xs8[0][(2 * yp) * R8 + xi];
    const half8_t* const rd8_1 = &xs8[1][(2 * yp) * R8 + xi];
    const half8_t* const rd8_2 = &xs8[2][(2 * yp) * R8 + xi];
    const half8_t* const rd8_3 = &xs8[3][(2 * yp) * R8 + xi];

    float4 S4a = make_float4(0.f, 0.f, 0.f, 0.f);
    float4 S4b = make_float4(0.f, 0.f, 0.f, 0.f);
    float STa = 0.f, STb = 0.f, acc = 0.f;

    // two producer prefetch sets: A = even slices, B = odd slices
#define DECL_SET(S) \
    float4 SI0##S, SI1##S, SI2##S, ST0##S, ST1##S, ST2##S; \
    SI0##S = SI1##S = SI2##S = ST0##S = ST1##S = ST2##S = make_float4(0.f, 0.f, 0.f, 0.f);
    DECL_SET(A) DECL_SET(B)
#undef DECL_SET

#define PRELOAD(S, zz) { \
    const float* pI = baseI + (zz) * HW; \
    const float* pT = baseT + (zz) * HW; \
    SI0##S = *(const float4*)(pI + voff0); ST0##S = *(const float4*)(pT + voff0); \
    SI1##S = *(const float4*)(pI + voff1); ST1##S = *(const float4*)(pT + voff1); \
    SI2##S = *(const float4*)(pI + voff2); ST2##S = *(const float4*)(pT + voff2); }

#define F4E(v, e) ((e) == 0 ? (v).x : ((e) == 1 ? (v).y : ((e) == 2 ? (v).z : (v).w)))

    // 9-tap sliding windows (4 outputs from 12 inputs), same fold as before
#define WIN4(PP, W) { \
    float ss = PP[0] + PP[1] + PP[2] + PP[3] + PP[4] + PP[5] + PP[6] + PP[7] + PP[8]; \
    W[0] = ss; ss += PP[9]  - PP[0]; W[1] = ss; \
               ss += PP[10] - PP[1]; W[2] = ss; \
               ss += PP[11] - PP[2]; W[3] = ss; }

    // compute + store one slice's x-windows (all 5 fields) from set S to SBP
#define PRODUCE(S, SBP) { \
    float Im[12], Tr[12], p[12]; \
    float wII[4], wIT[4], wTT[4], wI[4], wT[4]; \
    _Pragma("unroll") \
    for (int e = 0; e < 4; ++e) { \
        Im[e]     = F4E(SI0##S, e) * m0;  Tr[e]     = fmaf(F4E(ST0##S, e), 0.5f, 0.5f); \
        Im[4 + e] = F4E(SI1##S, e) * m1;  Tr[4 + e] = fmaf(F4E(ST1##S, e), 0.5f, 0.5f); \
        Im[8 + e] = F4E(SI2##S, e) * m2;  Tr[8 + e] = fmaf(F4E(ST2##S, e), 0.5f, 0.5f); } \
    _Pragma("unroll") \
    for (int i = 0; i < 12; ++i) \
        p[i] = Im[i] * F4E((i < 4 ? SI0##S : (i < 8 ? SI1##S : SI2##S)), i & 3); \
    WIN4(p, wII) \
    _Pragma("unroll") \
    for (int i = 0; i < 12; ++i) p[i] = Im[i] * Tr[i]; \
    WIN4(p, wIT) \
    WIN4(Im, wI) \
    _Pragma("unroll") \
    for (int i = 0; i < 12; ++i) Im[i] = Tr[i] * (i < 4 ? m0 : (i < 8 ? m1 : m2)); \
    _Pragma("unroll") \
    for (int i = 0; i < 12; ++i) p[i] = Im[i] * Tr[i]; \
    WIN4(p, wTT) \
    WIN4(Im, wT) \
    _Pragma("unroll") \
    for (int cc = 0; cc < 4; ++cc) { \
        const half2_t v01 = {(half_t)wII[cc], (half_t)wIT[cc]}; \
        const half2_t v23 = {(half_t)wTT[cc], (half_t)wI[cc]}; \
        ((half2_t*)(SBP))[cc * 4]     = v01; \
        ((half2_t*)(SBP))[cc * 4 + 1] = v23; \
        (SBP)[cc * 8 + 4] = (half_t)wT[cc]; } }

    // consumer body for ONE slice S from RD8, ring slot SLOT (literal)
#define CONSUME(S, RD8, SLOT) { \
    const int zi = z0 - 4 + (S); \
    const bool zok = (zi >= 0) && (zi < Dd); \
    half2_t a01_0 = (half2_t)0, a23_0 = (half2_t)0; \
    half2_t a01_1 = (half2_t)0, a23_1 = (half2_t)0; \
    half_t aT0 = (half_t)0.f, aT1 = (half_t)0.f; \
    if (zok && p2on) { \
        const half8_t w0 = (RD8)[0]; \
        const half8_t w9 = (RD8)[9 * R8]; \
        half2_t m01 = (half2_t)0, m23 = (half2_t)0, m4 = (half2_t)0; \
        _Pragma("unroll") \
        for (int kk = 1; kk < 9; ++kk) { \
            const half8_t w = (RD8)[kk * R8]; \
            const half2_t* wp = (const half2_t*)&w; \
            m01 += wp[0]; m23 += wp[1]; m4 += wp[2]; \
        } \
        const half2_t* w0p = (const half2_t*)&w0; \
        const half2_t* w9p = (const half2_t*)&w9; \
        a01_0 = m01 + w0p[0]; a23_0 = m23 + w0p[1]; aT0 = m4.x + w0p[2].x; \
        a01_1 = m01 + w9p[0]; a23_1 = m23 + w9p[1]; aT1 = m4.x + w9p[2].x; \
    } \
    if (p2on) { /* LDS z-ring shift + accumulate, b128 pair, literal slot */ \
        half8_t* const rAB8 = (half8_t*)&ringAB[(SLOT) * 256 + 2 * tid]; \
        half2_t* const rT  = (half2_t*)&ringT[(SLOT) * 256 + 2 * tid]; \
        const half8_t oA = *rAB8; \
        const half2_t oT = *rT; \
        S4a.x += (float)a01_0.x - (float)oA[0]; \
        S4a.y += (float)a01_0.y - (float)oA[1]; \
        S4a.z += (float)a23_0.x - (float)oA[2]; \
        S4a.w += (float)a23_0.y - (float)oA[3]; \
        STa   += (float)aT0 - (float)oT.x; \
        S4b.x += (float)a01_1.x - (float)oA[4]; \
        S4b.y += (float)a01_1.y - (float)oA[5]; \
        S4b.z += (float)a23_1.x - (float)oA[6]; \
        S4b.w += (float)a23_1.y - (float)oA[7]; \
        STb   += (float)aT1 - (float)oT.y; \
        const half8_t nA = {a01_0.x, a01_0.y, a23_0.x, a23_0.y, \
                            a01_1.x, a01_1.y, a23_1.x, a23_1.y}; \
        *rAB8 = nA; \
        const half2_t nT = {aT0, aT1}; \
        *rT = nT; \
    } \
    if ((S) >= 8 && p2on) {                   /* output z = z0+S-8 */ \
        { const float sii = S4a.x, sit = S4a.y, stt = S4a.z, si = S4a.w, stv = STa; \
          const float cross = sit - si * stv * INV_K; \
          const float tvar  = stt - stv * stv * INV_K; \
          const float ivar  = sii - si  * si  * INV_K; \
          acc += cross * cross * __builtin_amdgcn_rcpf(tvar * ivar + 1e-5f); } \
        { const float sii = S4b.x, sit = S4b.y, stt = S4b.z, si = S4b.w, stv = STb; \
          const float cross = sit - si * stv * INV_K; \
          const float tvar  = stt - stv * stv * INV_K; \
          const float ivar  = sii - si  * si  * INV_K; \
          acc += cross * cross * __builtin_amdgcn_rcpf(tvar * ivar + 1e-5f); } \
    } }

    // ---- prologue: produce slices 0,1 into buf0,buf1; preload slices 2,3
    if (isProd) {
        if (z0 - 4 >= 0) { PRELOAD(A, z0 - 4) PRODUCE(A, sb0) }
        if (z0 - 3 >= 0) { PRELOAD(B, z0 - 3) PRODUCE(B, sb1) }
        if (z0 - 2 >= 0) PRELOAD(A, z0 - 2)
        if (z0 - 1 >= 0) PRELOAD(B, z0 - 1)
    }
    __syncthreads();

    // one paired step j: producer makes slices 2j+2,2j+3 into PB0,PB1 and
    // preloads 2j+4,2j+5; consumer eats 2j,2j+1 from CB0,CB1. One barrier.
#define STEP_BODY(JJ, SL0, SL1, CB0, CB1, PB0, PB1) { \
    const int j = jb + (JJ); \
    const int s0 = 2 * j; \
    if (isProd) { \
        const int za = z0 - 2 + s0;             /* z of slice s0+2 */ \
        if ((s0 + 2) < LIVE && za >= 0 && za < Dd) PRODUCE(A, sb##PB0) \
        const int zb = za + 1;                  /* z of slice s0+3 */ \
        if ((s0 + 3) < LIVE && zb >= 0 && zb < Dd) PRODUCE(B, sb##PB1) \
        if ((s0 + 4) < LIVE && (za + 2) < Dd) PRELOAD(A, za + 2) \
        if ((s0 + 5) < LIVE && (zb + 2) < Dd) PRELOAD(B, zb + 2) \
    } \
    CONSUME(s0,     rd8_##CB0, SL0) \
    CONSUME(s0 + 1, rd8_##CB1, SL1) \
    __syncthreads(); }

#define STEP(JJ, SL0, SL1, CB0, CB1, PB0, PB1) \
    if (jb + (JJ) < NSTEP) STEP_BODY(JJ, SL0, SL1, CB0, CB1, PB0, PB1)

    for (int jb = 0; jb < 54; jb += 18) {          // 44 steps; 18-expansion x 3
        STEP(0,  0, 1, 0, 1, 2, 3)  STEP(1,  2, 3, 2, 3, 0, 1)
        STEP(2,  4, 5, 0, 1, 2, 3)  STEP(3,  6, 7, 2, 3, 0, 1)
        STEP(4,  8, 0, 0, 1, 2, 3)  STEP(5,  1, 2, 2, 3, 0, 1)
        STEP(6,  3, 4, 0, 1, 2, 3)  STEP(7,  5, 6, 2, 3, 0, 1)
        STEP(8,  7, 8, 0, 1, 2, 3)  STEP(9,  0, 1, 2, 3, 0, 1)
        STEP(10, 2, 3, 0, 1, 2, 3)  STEP(11, 4, 5, 2, 3, 0, 1)
        STEP(12, 6, 7, 0, 1, 2, 3)  STEP(13, 8, 0, 2, 3, 0, 1)
        STEP(14, 1, 2, 0, 1, 2, 3)  STEP(15, 3, 4, 2, 3, 0, 1)
        STEP(16, 5, 6, 0, 1, 2, 3)  STEP(17, 7, 8, 2, 3, 0, 1)
    }
#undef STEP
#undef STEP_BODY
#undef CONSUME
#undef PRODUCE
#undef WIN4
#undef F4E
#undef PRELOAD

    // ---- block reduction + fused finalize (one atomic per block)
    #pragma unroll
    for (int off = 32; off > 0; off >>= 1) acc += __shfl_down(acc, off, 64);
    if ((tid & 63) == 0) red[tid >> 6] = acc;
    __syncthreads();
    if (tid == 0) {
        const float tot = red[0] + red[1] + red[2] + red[3];
        atomicAdd(out, -tot * INV_TOT);
    }
}

} // namespace

extern "C" void kernel_launch(void* const* d_in, const int* in_sizes, int n_in,
                              void* d_out, int out_size, void* d_ws, size_t ws_size,
                              hipStream_t stream)
{
    const float* inp = (const float*)d_in[0];
    const float* tgt = (const float*)d_in[1];
    float* out = (float*)d_out;

    hipMemsetAsync(d_out, 0, sizeof(float), stream);   // d_out re-poisoned each call
    dim3 grid(Wd / TX, Hd / TY, 2 * (Dd / CZ));        // (10,12,4) = 480 blocks
    ncc_main<<<grid, 256, 0, stream>>>(inp, tgt, out);
}